// Round 1
// baseline (607.799 us; speedup 1.0000x reference)
//
#include <hip/hip_runtime.h>
#include <hip/hip_bf16.h>
#include <stdint.h>

// ---------- types ----------
typedef __bf16 bf16x8 __attribute__((ext_vector_type(8)));
typedef float  f32x4  __attribute__((ext_vector_type(4)));
typedef uint16_t u16x8 __attribute__((ext_vector_type(8)));

__device__ __forceinline__ uint16_t f32_to_bf16(float f) {
    union { float f; uint32_t u; } v; v.f = f;
    uint32_t u = v.u;
    uint32_t r = (u + 0x7FFFu + ((u >> 16) & 1u)) >> 16;
    return (uint16_t)r;
}
__device__ __forceinline__ float bf16_to_f32(uint16_t b) {
    union { uint32_t u; float f; } v; v.u = ((uint32_t)b) << 16;
    return v.f;
}

// async global->LDS, 16B per lane. LDS dest semantics: wave-uniform base + lane*16.
__device__ __forceinline__ void gld16(const uint16_t* g, uint16_t* l) {
    __builtin_amdgcn_global_load_lds(
        (const __attribute__((address_space(1))) void*)g,
        (__attribute__((address_space(3))) void*)l,
        16, 0, 0);
}

// ---------- elementwise cast fp32 -> bf16 ----------
__global__ __launch_bounds__(256) void cast_f32_bf16_kernel(
    const float* __restrict__ in, uint16_t* __restrict__ out) {
    size_t i = ((size_t)blockIdx.x * 256 + threadIdx.x) * 4;
    float4 f = *(const float4*)(in + i);
    ushort4 o;
    o.x = f32_to_bf16(f.x); o.y = f32_to_bf16(f.y);
    o.z = f32_to_bf16(f.z); o.w = f32_to_bf16(f.w);
    *(ushort4*)(out + i) = o;
}

// ---------- W [K=1024][N=1024] f32  ->  Wt [N][K] bf16 ----------
__global__ __launch_bounds__(256) void wtrans_kernel(
    const float* __restrict__ W, uint16_t* __restrict__ Wt) {
    __shared__ float tile[64][65];
    const int n0 = blockIdx.x * 64, k0 = blockIdx.y * 64;
    const int tx = threadIdx.x & 63, ty0 = threadIdx.x >> 6;
#pragma unroll
    for (int r = 0; r < 16; ++r) {
        int ty = ty0 + r * 4;
        tile[ty][tx] = W[(size_t)(k0 + ty) * 1024 + n0 + tx];
    }
    __syncthreads();
#pragma unroll
    for (int r = 0; r < 16; ++r) {
        int ty = ty0 + r * 4;
        Wt[(size_t)(n0 + ty) * 1024 + k0 + tx] = f32_to_bf16(tile[tx][ty]);
    }
}

// ---------- V [b][2048][1024] bf16 -> Vt [b][1024][2048] bf16 ----------
__global__ __launch_bounds__(256) void vtrans_kernel(
    const uint16_t* __restrict__ V, uint16_t* __restrict__ Vt) {
    const int b = blockIdx.z;
    const uint16_t* Vp = V + (size_t)b * 2048 * 1024;
    uint16_t* Vtp = Vt + (size_t)b * 1024 * 2048;
    __shared__ uint16_t tile[64][65];
    const int d0 = blockIdx.x * 64, s0 = blockIdx.y * 64;
    const int tx = threadIdx.x & 63, ty0 = threadIdx.x >> 6;
#pragma unroll
    for (int r = 0; r < 16; ++r) {
        int ty = ty0 + r * 4;  // s index
        tile[ty][tx] = Vp[(size_t)(s0 + ty) * 1024 + d0 + tx];
    }
    __syncthreads();
#pragma unroll
    for (int r = 0; r < 16; ++r) {
        int ty = ty0 + r * 4;  // d index
        Vtp[(size_t)(d0 + ty) * 2048 + s0 + tx] = tile[tx][ty];
    }
}

// ---------- NT GEMM: C[M,N] = alpha * A[M,K] @ B[N,K]^T (+ bias[n]) ----------
// A,B row-major bf16 (contraction dim contiguous). 128x128x32 tile, 256 thr.
template <bool OUT_BF16, bool HAS_BIAS>
__global__ __launch_bounds__(256, 2) void gemm_nt_kernel(
    const uint16_t* __restrict__ A, long long lda, long long sAz,
    const uint16_t* __restrict__ B, long long ldb, long long sBz,
    void* __restrict__ Cv, long long ldc, long long sCz,
    int K, float alpha, const float* __restrict__ bias) {
    __shared__ __align__(16) uint16_t As[128 * 32];
    __shared__ __align__(16) uint16_t Bs[128 * 32];

    const int tid  = threadIdx.x;
    const int lane = tid & 63;
    const int wave = tid >> 6;
    const int z = blockIdx.z;
    A += (size_t)z * sAz;
    B += (size_t)z * sBz;
    const int row0 = blockIdx.y * 128;
    const int col0 = blockIdx.x * 128;

    // staging chunks: chunk c = tid + 256*t covers tile row c>>2, k-offset (c&3)*8.
    // LDS element offset of chunk = c*8 (so dest = wave base + lane*16B holds).
    const int c0 = tid, c1 = tid + 256;
    const int ar0 = c0 >> 2, ak0 = (c0 & 3) * 8;
    const int ar1 = c1 >> 2, ak1 = (c1 & 3) * 8;

    const int wr = wave >> 1, wc = wave & 1;
    const int mrow = lane & 15;
    const int quad = lane >> 4;

    f32x4 acc[4][4];
#pragma unroll
    for (int i = 0; i < 4; ++i)
#pragma unroll
        for (int j = 0; j < 4; ++j) acc[i][j] = 0.0f;

    for (int k0 = 0; k0 < K; k0 += 32) {
        __syncthreads();  // previous iter's LDS reads done before overwrite
        gld16(A + (size_t)(row0 + ar0) * lda + k0 + ak0, &As[(size_t)c0 * 8]);
        gld16(A + (size_t)(row0 + ar1) * lda + k0 + ak1, &As[(size_t)c1 * 8]);
        gld16(B + (size_t)(col0 + ar0) * ldb + k0 + ak0, &Bs[(size_t)c0 * 8]);
        gld16(B + (size_t)(col0 + ar1) * ldb + k0 + ak1, &Bs[(size_t)c1 * 8]);
        __syncthreads();  // staging complete

        bf16x8 af[4], bfj[4];
#pragma unroll
        for (int i = 0; i < 4; ++i)
            af[i] = *(const bf16x8*)&As[(size_t)(wr * 64 + i * 16 + mrow) * 32 + quad * 8];
#pragma unroll
        for (int j = 0; j < 4; ++j)
            bfj[j] = *(const bf16x8*)&Bs[(size_t)(wc * 64 + j * 16 + mrow) * 32 + quad * 8];
#pragma unroll
        for (int i = 0; i < 4; ++i)
#pragma unroll
            for (int j = 0; j < 4; ++j)
                acc[i][j] = __builtin_amdgcn_mfma_f32_16x16x32_bf16(
                    af[i], bfj[j], acc[i][j], 0, 0, 0);
    }

    // epilogue: C/D layout col=lane&15, row=quad*4+reg (m89-verified)
    if (OUT_BF16) {
        uint16_t* C = (uint16_t*)Cv + (size_t)z * sCz;
#pragma unroll
        for (int i = 0; i < 4; ++i)
#pragma unroll
            for (int j = 0; j < 4; ++j)
#pragma unroll
                for (int r = 0; r < 4; ++r) {
                    int row = row0 + wr * 64 + i * 16 + quad * 4 + r;
                    int col = col0 + wc * 64 + j * 16 + mrow;
                    float val = acc[i][j][r] * alpha;
                    if (HAS_BIAS) val += bias[col];
                    C[(size_t)row * ldc + col] = f32_to_bf16(val);
                }
    } else {
        float* C = (float*)Cv + (size_t)z * sCz;
#pragma unroll
        for (int i = 0; i < 4; ++i)
#pragma unroll
            for (int j = 0; j < 4; ++j)
#pragma unroll
                for (int r = 0; r < 4; ++r) {
                    int row = row0 + wr * 64 + i * 16 + quad * 4 + r;
                    int col = col0 + wc * 64 + j * 16 + mrow;
                    float val = acc[i][j][r] * alpha;
                    if (HAS_BIAS) val += bias[col];
                    C[(size_t)row * ldc + col] = val;
                }
    }
}

// ---------- row softmax over 2048 bf16, in place, normalized ----------
__global__ __launch_bounds__(256) void softmax_kernel(uint16_t* __restrict__ Sc) {
    __shared__ float red[4];
    uint16_t* p = Sc + (size_t)blockIdx.x * 2048;
    const int tid = threadIdx.x;
    u16x8 v = *(const u16x8*)(p + tid * 8);
    float f[8];
#pragma unroll
    for (int i = 0; i < 8; ++i) f[i] = bf16_to_f32(v[i]);

    float m = f[0];
#pragma unroll
    for (int i = 1; i < 8; ++i) m = fmaxf(m, f[i]);
#pragma unroll
    for (int off = 32; off; off >>= 1) m = fmaxf(m, __shfl_xor(m, off, 64));
    if ((tid & 63) == 0) red[tid >> 6] = m;
    __syncthreads();
    m = fmaxf(fmaxf(red[0], red[1]), fmaxf(red[2], red[3]));

    float e[8], s = 0.0f;
#pragma unroll
    for (int i = 0; i < 8; ++i) { e[i] = __expf(f[i] - m); s += e[i]; }
#pragma unroll
    for (int off = 32; off; off >>= 1) s += __shfl_xor(s, off, 64);
    __syncthreads();  // protect red[] reuse
    if ((tid & 63) == 0) red[tid >> 6] = s;
    __syncthreads();
    s = (red[0] + red[1]) + (red[2] + red[3]);
    float inv = 1.0f / s;

    u16x8 o;
#pragma unroll
    for (int i = 0; i < 8; ++i) o[i] = f32_to_bf16(e[i] * inv);
    *(u16x8*)(p + tid * 8) = o;
}

// ---------- launch ----------
extern "C" void kernel_launch(void* const* d_in, const int* in_sizes, int n_in,
                              void* d_out, int out_size, void* d_ws, size_t ws_size,
                              hipStream_t stream) {
    const float* in_k = (const float*)d_in[0];
    const float* in_q = (const float*)d_in[1];
    const float* in_v = (const float*)d_in[2];
    const float* Wk = (const float*)d_in[3];
    const float* bk = (const float*)d_in[4];
    const float* Wq = (const float*)d_in[5];
    const float* bq = (const float*)d_in[6];
    const float* Wv = (const float*)d_in[7];
    const float* bv = (const float*)d_in[8];
    float* out = (float*)d_out;

    // ws layout (bytes). Total needed: 198 MB.
    char* w = (char*)d_ws;
    uint16_t* Xq  = (uint16_t*)(w + 0);            // 32 MB  (dead after proj -> Sc lo)
    uint16_t* Xk  = (uint16_t*)(w + 33554432);     // 32 MB  (dead after proj -> Sc hi)
    uint16_t* Xv  = (uint16_t*)(w + 67108864);     // 32 MB  (dead after proj -> Vt)
    uint16_t* Qb  = (uint16_t*)(w + 100663296);    // 32 MB
    uint16_t* Kb  = (uint16_t*)(w + 134217728);    // 32 MB
    uint16_t* Vb  = (uint16_t*)(w + 167772160);    // 32 MB
    uint16_t* Wqt = (uint16_t*)(w + 201326592);    // 2 MB
    uint16_t* Wkt = (uint16_t*)(w + 203423744);    // 2 MB
    uint16_t* Wvt = (uint16_t*)(w + 205520896);    // 2 MB
    uint16_t* Sc  = Xq;                            // 64 MB overlay (Xq+Xk)
    uint16_t* Vt  = Xv;                            // 32 MB overlay

    // 1. casts
    cast_f32_bf16_kernel<<<16384, 256, 0, stream>>>(in_q, Xq);
    cast_f32_bf16_kernel<<<16384, 256, 0, stream>>>(in_k, Xk);
    cast_f32_bf16_kernel<<<16384, 256, 0, stream>>>(in_v, Xv);
    wtrans_kernel<<<dim3(16, 16), 256, 0, stream>>>(Wq, Wqt);
    wtrans_kernel<<<dim3(16, 16), 256, 0, stream>>>(Wk, Wkt);
    wtrans_kernel<<<dim3(16, 16), 256, 0, stream>>>(Wv, Wvt);

    // 2. projections: [16384,1024] = X @ Wt^T + b
    gemm_nt_kernel<true, true><<<dim3(8, 128, 1), 256, 0, stream>>>(
        Xq, 1024, 0, Wqt, 1024, 0, Qb, 1024, 0, 1024, 1.0f, bq);
    gemm_nt_kernel<true, true><<<dim3(8, 128, 1), 256, 0, stream>>>(
        Xk, 1024, 0, Wkt, 1024, 0, Kb, 1024, 0, 1024, 1.0f, bk);
    gemm_nt_kernel<true, true><<<dim3(8, 128, 1), 256, 0, stream>>>(
        Xv, 1024, 0, Wvt, 1024, 0, Vb, 1024, 0, 1024, 1.0f, bv);

    // 3. V -> Vt
    vtrans_kernel<<<dim3(16, 32, 8), 256, 0, stream>>>(Vb, Vt);

    // 4. scores: Sc[b] = (1/32) * Q[b] @ K[b]^T   [2048 x 2048] bf16
    gemm_nt_kernel<true, false><<<dim3(16, 16, 8), 256, 0, stream>>>(
        Qb, 1024, 2048LL * 1024, Kb, 1024, 2048LL * 1024,
        Sc, 2048, 2048LL * 2048, 1024, 0.03125f, nullptr);

    // 5. softmax rows (normalized, in place)
    softmax_kernel<<<16384, 256, 0, stream>>>(Sc);

    // 6. out[b] = P[b] @ Vt[b]^T  -> fp32 d_out
    gemm_nt_kernel<false, false><<<dim3(8, 16, 8), 256, 0, stream>>>(
        Sc, 2048, 2048LL * 2048, Vt, 2048, 1024LL * 2048,
        out, 1024, 2048LL * 1024, 2048, 1.0f, nullptr);
}

// Round 2
// 553.269 us; speedup vs baseline: 1.0986x; 1.0986x over previous
//
#include <hip/hip_runtime.h>
#include <hip/hip_bf16.h>
#include <stdint.h>

// ---------- types ----------
typedef __bf16 bf16x8 __attribute__((ext_vector_type(8)));
typedef float  f32x4  __attribute__((ext_vector_type(4)));
typedef uint16_t u16x8 __attribute__((ext_vector_type(8)));

__device__ __forceinline__ uint16_t f32_to_bf16(float f) {
    union { float f; uint32_t u; } v; v.f = f;
    uint32_t u = v.u;
    uint32_t r = (u + 0x7FFFu + ((u >> 16) & 1u)) >> 16;
    return (uint16_t)r;
}
__device__ __forceinline__ float bf16_to_f32(uint16_t b) {
    union { uint32_t u; float f; } v; v.u = ((uint32_t)b) << 16;
    return v.f;
}

// async global->LDS, 16B per lane. LDS dest semantics: wave-uniform base + lane*16.
__device__ __forceinline__ void gld16(const uint16_t* g, uint16_t* l) {
    __builtin_amdgcn_global_load_lds(
        (const __attribute__((address_space(1))) void*)g,
        (__attribute__((address_space(3))) void*)l,
        16, 0, 0);
}

// ---------- elementwise cast fp32 -> bf16 ----------
__global__ __launch_bounds__(256) void cast_f32_bf16_kernel(
    const float* __restrict__ in, uint16_t* __restrict__ out) {
    size_t i = ((size_t)blockIdx.x * 256 + threadIdx.x) * 4;
    float4 f = *(const float4*)(in + i);
    ushort4 o;
    o.x = f32_to_bf16(f.x); o.y = f32_to_bf16(f.y);
    o.z = f32_to_bf16(f.z); o.w = f32_to_bf16(f.w);
    *(ushort4*)(out + i) = o;
}

// ---------- W [K=1024][N=1024] f32  ->  Wt [N][K] bf16 ----------
__global__ __launch_bounds__(256) void wtrans_kernel(
    const float* __restrict__ W, uint16_t* __restrict__ Wt) {
    __shared__ float tile[64][65];
    const int n0 = blockIdx.x * 64, k0 = blockIdx.y * 64;
    const int tx = threadIdx.x & 63, ty0 = threadIdx.x >> 6;
#pragma unroll
    for (int r = 0; r < 16; ++r) {
        int ty = ty0 + r * 4;
        tile[ty][tx] = W[(size_t)(k0 + ty) * 1024 + n0 + tx];
    }
    __syncthreads();
#pragma unroll
    for (int r = 0; r < 16; ++r) {
        int ty = ty0 + r * 4;
        Wt[(size_t)(n0 + ty) * 1024 + k0 + tx] = f32_to_bf16(tile[tx][ty]);
    }
}

// ---------- V [b][2048][1024] bf16 -> Vt [b][1024][2048] bf16 ----------
__global__ __launch_bounds__(256) void vtrans_kernel(
    const uint16_t* __restrict__ V, uint16_t* __restrict__ Vt) {
    const int b = blockIdx.z;
    const uint16_t* Vp = V + (size_t)b * 2048 * 1024;
    uint16_t* Vtp = Vt + (size_t)b * 1024 * 2048;
    __shared__ uint16_t tile[64][65];
    const int d0 = blockIdx.x * 64, s0 = blockIdx.y * 64;
    const int tx = threadIdx.x & 63, ty0 = threadIdx.x >> 6;
#pragma unroll
    for (int r = 0; r < 16; ++r) {
        int ty = ty0 + r * 4;  // s index
        tile[ty][tx] = Vp[(size_t)(s0 + ty) * 1024 + d0 + tx];
    }
    __syncthreads();
#pragma unroll
    for (int r = 0; r < 16; ++r) {
        int ty = ty0 + r * 4;  // d index
        Vtp[(size_t)(d0 + ty) * 2048 + s0 + tx] = tile[tx][ty];
    }
}

// ---------- NT GEMM: C[M,N] = alpha * A[M,K] @ B[N,K]^T (+ bias[n]) ----------
// A,B row-major bf16 (contraction dim contiguous). 128x128x32 tile, 256 thr.
// 1D grid = Z * tM * tN. Block mapping:
//   z = bid % Z            (batch pinned to XCD under %8 round-robin heuristic)
//   band-major within batch: 8 M-tiles per band, N-major inside the band, so a
//   band's L2 working set = 8 A-slabs (2 MB) + B stream.
// LDS k-chunk XOR swizzle s(row)=(row>>1)&3 kills the 8-way ds_read_b128 bank
// conflict of the naive [row][32] layout (2-way residual = free, m136).
template <bool OUT_BF16, bool HAS_BIAS>
__global__ __launch_bounds__(256, 2) void gemm_nt_kernel(
    const uint16_t* __restrict__ A, long long lda, long long sAz,
    const uint16_t* __restrict__ B, long long ldb, long long sBz,
    void* __restrict__ Cv, long long ldc, long long sCz,
    int K, float alpha, const float* __restrict__ bias,
    int Z, int tN) {
    __shared__ __align__(16) uint16_t As[128 * 32];
    __shared__ __align__(16) uint16_t Bs[128 * 32];

    const int tid  = threadIdx.x;
    const int lane = tid & 63;
    const int wave = tid >> 6;

    const int bid = blockIdx.x;
    const int z = bid % Z;
    const int t = bid / Z;
    const int bandSz = tN * 8;
    const int band = t / bandSz;
    const int r0 = t - band * bandSz;
    const int my = band * 8 + (r0 & 7);
    const int mx = r0 >> 3;

    A += (size_t)z * sAz;
    B += (size_t)z * sBz;
    const int row0 = my * 128;
    const int col0 = mx * 128;

    // staging: chunk c (c = tid, tid+256) -> LDS slot c*8 elements (fixed by
    // global_load_lds lane semantics). Chunk c fetches global
    // (row = c>>2, kchunk = (c&3) ^ s(row)), s(row) = (row>>1)&3.
    const int c0 = tid, c1 = tid + 256;
    const int ar0 = c0 >> 2, ak0 = (((c0 & 3) ^ ((ar0 >> 1) & 3))) * 8;
    const int ar1 = c1 >> 2, ak1 = (((c1 & 3) ^ ((ar1 >> 1) & 3))) * 8;

    const int wr = wave >> 1, wc = wave & 1;
    const int mrow = lane & 15;
    const int quad = lane >> 4;
    const int sw = (mrow >> 1) & 3;          // == (row>>1)&3 for all fragment rows
    const int qsw = (quad ^ sw) * 8;

    f32x4 acc[4][4];
#pragma unroll
    for (int i = 0; i < 4; ++i)
#pragma unroll
        for (int j = 0; j < 4; ++j) acc[i][j] = 0.0f;

    for (int k0 = 0; k0 < K; k0 += 32) {
        __syncthreads();  // previous iter's LDS reads done before overwrite
        gld16(A + (size_t)(row0 + ar0) * lda + k0 + ak0, &As[(size_t)c0 * 8]);
        gld16(A + (size_t)(row0 + ar1) * lda + k0 + ak1, &As[(size_t)c1 * 8]);
        gld16(B + (size_t)(col0 + ar0) * ldb + k0 + ak0, &Bs[(size_t)c0 * 8]);
        gld16(B + (size_t)(col0 + ar1) * ldb + k0 + ak1, &Bs[(size_t)c1 * 8]);
        __syncthreads();  // staging complete

        bf16x8 af[4], bfj[4];
#pragma unroll
        for (int i = 0; i < 4; ++i)
            af[i] = *(const bf16x8*)&As[(size_t)(wr * 64 + i * 16 + mrow) * 32 + qsw];
#pragma unroll
        for (int j = 0; j < 4; ++j)
            bfj[j] = *(const bf16x8*)&Bs[(size_t)(wc * 64 + j * 16 + mrow) * 32 + qsw];
#pragma unroll
        for (int i = 0; i < 4; ++i)
#pragma unroll
            for (int j = 0; j < 4; ++j)
                acc[i][j] = __builtin_amdgcn_mfma_f32_16x16x32_bf16(
                    af[i], bfj[j], acc[i][j], 0, 0, 0);
    }

    // epilogue: C/D layout col=lane&15, row=quad*4+reg (m89-verified)
    if (OUT_BF16) {
        uint16_t* C = (uint16_t*)Cv + (size_t)z * sCz;
#pragma unroll
        for (int i = 0; i < 4; ++i)
#pragma unroll
            for (int j = 0; j < 4; ++j)
#pragma unroll
                for (int r = 0; r < 4; ++r) {
                    int row = row0 + wr * 64 + i * 16 + quad * 4 + r;
                    int col = col0 + wc * 64 + j * 16 + mrow;
                    float val = acc[i][j][r] * alpha;
                    if (HAS_BIAS) val += bias[col];
                    C[(size_t)row * ldc + col] = f32_to_bf16(val);
                }
    } else {
        float* C = (float*)Cv + (size_t)z * sCz;
#pragma unroll
        for (int i = 0; i < 4; ++i)
#pragma unroll
            for (int j = 0; j < 4; ++j)
#pragma unroll
                for (int r = 0; r < 4; ++r) {
                    int row = row0 + wr * 64 + i * 16 + quad * 4 + r;
                    int col = col0 + wc * 64 + j * 16 + mrow;
                    float val = acc[i][j][r] * alpha;
                    if (HAS_BIAS) val += bias[col];
                    C[(size_t)row * ldc + col] = val;
                }
    }
}

// ---------- row softmax over 2048 bf16, in place, normalized ----------
__global__ __launch_bounds__(256) void softmax_kernel(uint16_t* __restrict__ Sc) {
    __shared__ float red[4];
    uint16_t* p = Sc + (size_t)blockIdx.x * 2048;
    const int tid = threadIdx.x;
    u16x8 v = *(const u16x8*)(p + tid * 8);
    float f[8];
#pragma unroll
    for (int i = 0; i < 8; ++i) f[i] = bf16_to_f32(v[i]);

    float m = f[0];
#pragma unroll
    for (int i = 1; i < 8; ++i) m = fmaxf(m, f[i]);
#pragma unroll
    for (int off = 32; off; off >>= 1) m = fmaxf(m, __shfl_xor(m, off, 64));
    if ((tid & 63) == 0) red[tid >> 6] = m;
    __syncthreads();
    m = fmaxf(fmaxf(red[0], red[1]), fmaxf(red[2], red[3]));

    float e[8], s = 0.0f;
#pragma unroll
    for (int i = 0; i < 8; ++i) { e[i] = __expf(f[i] - m); s += e[i]; }
#pragma unroll
    for (int off = 32; off; off >>= 1) s += __shfl_xor(s, off, 64);
    __syncthreads();  // protect red[] reuse
    if ((tid & 63) == 0) red[tid >> 6] = s;
    __syncthreads();
    s = (red[0] + red[1]) + (red[2] + red[3]);
    float inv = 1.0f / s;

    u16x8 o;
#pragma unroll
    for (int i = 0; i < 8; ++i) o[i] = f32_to_bf16(e[i] * inv);
    *(u16x8*)(p + tid * 8) = o;
}

// ---------- launch ----------
extern "C" void kernel_launch(void* const* d_in, const int* in_sizes, int n_in,
                              void* d_out, int out_size, void* d_ws, size_t ws_size,
                              hipStream_t stream) {
    const float* in_k = (const float*)d_in[0];
    const float* in_q = (const float*)d_in[1];
    const float* in_v = (const float*)d_in[2];
    const float* Wk = (const float*)d_in[3];
    const float* bk = (const float*)d_in[4];
    const float* Wq = (const float*)d_in[5];
    const float* bq = (const float*)d_in[6];
    const float* Wv = (const float*)d_in[7];
    const float* bv = (const float*)d_in[8];
    float* out = (float*)d_out;

    // ws layout (bytes). Total needed: 198 MB.
    char* w = (char*)d_ws;
    uint16_t* Xq  = (uint16_t*)(w + 0);            // 32 MB  (dead after proj -> Sc lo)
    uint16_t* Xk  = (uint16_t*)(w + 33554432);     // 32 MB  (dead after proj -> Sc hi)
    uint16_t* Xv  = (uint16_t*)(w + 67108864);     // 32 MB  (dead after proj -> Vt)
    uint16_t* Qb  = (uint16_t*)(w + 100663296);    // 32 MB
    uint16_t* Kb  = (uint16_t*)(w + 134217728);    // 32 MB
    uint16_t* Vb  = (uint16_t*)(w + 167772160);    // 32 MB
    uint16_t* Wqt = (uint16_t*)(w + 201326592);    // 2 MB
    uint16_t* Wkt = (uint16_t*)(w + 203423744);    // 2 MB
    uint16_t* Wvt = (uint16_t*)(w + 205520896);    // 2 MB
    uint16_t* Sc  = Xq;                            // 64 MB overlay (Xq+Xk)
    uint16_t* Vt  = Xv;                            // 32 MB overlay

    // 1. casts
    cast_f32_bf16_kernel<<<16384, 256, 0, stream>>>(in_q, Xq);
    cast_f32_bf16_kernel<<<16384, 256, 0, stream>>>(in_k, Xk);
    cast_f32_bf16_kernel<<<16384, 256, 0, stream>>>(in_v, Xv);
    wtrans_kernel<<<dim3(16, 16), 256, 0, stream>>>(Wq, Wqt);
    wtrans_kernel<<<dim3(16, 16), 256, 0, stream>>>(Wk, Wkt);
    wtrans_kernel<<<dim3(16, 16), 256, 0, stream>>>(Wv, Wvt);

    // 2. projections: [16384,1024] = X @ Wt^T + b   (tM=128, tN=8, Z=1)
    gemm_nt_kernel<true, true><<<1024, 256, 0, stream>>>(
        Xq, 1024, 0, Wqt, 1024, 0, Qb, 1024, 0, 1024, 1.0f, bq, 1, 8);
    gemm_nt_kernel<true, true><<<1024, 256, 0, stream>>>(
        Xk, 1024, 0, Wkt, 1024, 0, Kb, 1024, 0, 1024, 1.0f, bk, 1, 8);
    gemm_nt_kernel<true, true><<<1024, 256, 0, stream>>>(
        Xv, 1024, 0, Wvt, 1024, 0, Vb, 1024, 0, 1024, 1.0f, bv, 1, 8);

    // 3. V -> Vt
    vtrans_kernel<<<dim3(16, 32, 8), 256, 0, stream>>>(Vb, Vt);

    // 4. scores: Sc[b] = (1/32) * Q[b] @ K[b]^T   [2048 x 2048] bf16
    //    tM=16, tN=16, Z=8 -> grid 2048
    gemm_nt_kernel<true, false><<<2048, 256, 0, stream>>>(
        Qb, 1024, 2048LL * 1024, Kb, 1024, 2048LL * 1024,
        Sc, 2048, 2048LL * 2048, 1024, 0.03125f, nullptr, 8, 16);

    // 5. softmax rows (normalized, in place)
    softmax_kernel<<<16384, 256, 0, stream>>>(Sc);

    // 6. out[b] = P[b] @ Vt[b]^T  -> fp32 d_out   (tM=16, tN=8, Z=8 -> grid 1024)
    gemm_nt_kernel<false, false><<<1024, 256, 0, stream>>>(
        Sc, 2048, 2048LL * 2048, Vt, 2048, 1024LL * 2048,
        out, 1024, 2048LL * 1024, 2048, 1.0f, nullptr, 8, 8);
}